// Round 6
// baseline (383.542 us; speedup 1.0000x reference)
//
#include <hip/hip_runtime.h>
#include <cstdint>

// B=4, T=4096, D=1024, H=16, d=64, C=64, N=T/C=64
#define B_ 4
#define T_ 4096
#define D_ 1024
#define H_ 16
#define HD_ 64
#define N_ 64

typedef __attribute__((ext_vector_type(8))) short s16x8;
typedef __attribute__((ext_vector_type(4))) float f32x4;

__device__ __forceinline__ unsigned short f2bf(float f) {
    unsigned int u = __builtin_bit_cast(unsigned int, f);
    u += 0x7fffu + ((u >> 16) & 1u);          // RNE
    return (unsigned short)(u >> 16);
}
__device__ __forceinline__ float bf2f(unsigned short h) {
    unsigned int u = ((unsigned int)h) << 16;
    return __builtin_bit_cast(float, u);
}
__device__ __forceinline__ void gl2lds(const short* g, short* l) {
    __builtin_amdgcn_global_load_lds(
        (const __attribute__((address_space(1))) void*)g,
        (__attribute__((address_space(3))) void*)l, 16, 0, 0);
}
#define MFMA16(a, b, c) __builtin_amdgcn_mfma_f32_16x16x32_bf16(a, b, c, 0, 0, 0)

// ---------------------------------------------------------------------------
// Converters.
// ---------------------------------------------------------------------------
__global__ __launch_bounds__(256)
void k_cvt_split(const float* __restrict__ in, short* __restrict__ out, int n4)
{
    int i = blockIdx.x * blockDim.x + threadIdx.x;
    const int stride = gridDim.x * blockDim.x;
    for (; i < n4; i += stride) {
        float4 f = ((const float4*)in)[i];
        const float v[4] = {f.x, f.y, f.z, f.w};
        s16x8 o;
        #pragma unroll
        for (int j = 0; j < 4; ++j) {
            unsigned short h = f2bf(v[j]);
            o[j*2]   = (short)h;
            o[j*2+1] = (short)f2bf(v[j] - bf2f(h));
        }
        ((s16x8*)out)[i] = o;
    }
}
__global__ __launch_bounds__(256)
void k_cvt(const float* __restrict__ in, short* __restrict__ out, int n4)
{
    int i = blockIdx.x * blockDim.x + threadIdx.x;
    const int stride = gridDim.x * blockDim.x;
    for (; i < n4; i += stride) {
        float4 f = ((const float4*)in)[i];
        short4 o;
        o.x = (short)f2bf(f.x); o.y = (short)f2bf(f.y);
        o.z = (short)f2bf(f.z); o.w = (short)f2bf(f.w);
        *(short4*)(out + i * 4) = o;
    }
}

// ---------------------------------------------------------------------------
// bf16 MFMA GEMM, 8-phase schedule (T3+T4+T5): O = A @ B^T.
// 256x256 tile, BK=64, 512 thr (8 waves, 2x4), 16x16x32 MFMA.
// LDS: [dbuf][A/B][kk-half][256 rows x 32 cols] bf16 = 4x 16KiB units/tile,
// 128 KiB total. Each K-tile = 4 phases: {stage 1 half-unit (2 gl2lds),
// ds_read 4-8 frags, barrier, lgkm(0), 16 MFMA (setprio), barrier}.
// kk0 slot dead after ph1 -> restaged for tile t+2 at ph2/ph3 (1.75-tile
// lookahead). Counted vmcnt(4) once per tile, never 0 in steady state.
// Swizzle: phys 16B slot = rg ^ ((R^(R>>2))&3), inverse applied on the
// gl2lds global source (both-sides rule).
// MODE 0: k/v epilogue (sign bf16 -> Kb+KbT or VbT). MODE 1: fp32 Y.
// MODE 2: Q epilogue (bf16, *0.125).
// ---------------------------------------------------------------------------
template<int MODE, int KD, int NCB>
__global__ __launch_bounds__(512, 2)
void k_gemm(const short* __restrict__ A, const short* __restrict__ Bm,
            short* __restrict__ O1, short* __restrict__ O2,
            short* __restrict__ O3, float* __restrict__ Yf)
{
    __shared__ __align__(16) short LS[2][2][2][8192];  // [dbuf][A/B][kk][256*32]

    const int tid = threadIdx.x;
    const int nwg = 64 * NCB;
    const int bid = blockIdx.x;
    const int sz  = (bid & 7) * (nwg >> 3) + (bid >> 3);   // XCD-contiguous
    const int cb  = sz % NCB, rb = sz / NCB;
    const int row0 = rb * 256, col0 = cb * 256;

    const int lane = tid & 63, w = tid >> 6;
    const int wr = w >> 2, wc = w & 3;
    const int cl = lane & 15, rg = lane >> 4;
    const int gc = (cl ^ (cl >> 2)) & 3;                   // read-side swizzle

    // staging: lane -> row (w*32 + c*16 + (lane>>2)), phys slot (lane&3);
    // global src pre-swizzled so phys slot p holds logical slot p^g(row).
    const int r16 = lane >> 2;
    const int sslot = (lane & 3) ^ ((r16 ^ (r16 >> 2)) & 3);
    const short* gA = A  + (size_t)(row0 + w * 32 + r16) * KD + sslot * 8;
    const short* gB = Bm + (size_t)(col0 + w * 32 + r16) * KD + sslot * 8;

    f32x4 acc[8][4];
    #pragma unroll
    for (int i = 0; i < 8; ++i)
        #pragma unroll
        for (int j = 0; j < 4; ++j) acc[i][j] = (f32x4)0.f;

    // stage one 16 KiB unit (2 gl2lds per thread): matrix mat, K-half kk, tile u
    auto stageU = [&](int mat, int kk, int u) {
        const short* g = (mat == 0) ? gA : gB;
        const int ko = u * 64 + kk * 32;
        short* dst = &LS[u & 1][mat][kk][(w * 32) * 32];
        gl2lds(g + ko, dst);
        gl2lds(g + (size_t)16 * KD + ko, dst + 16 * 32);
    };
    auto ldA = [&](int pb, int kk, int mih, s16x8* fa) {
        const char* base = (const char*)&LS[pb][0][kk][0];
        #pragma unroll
        for (int mi = 0; mi < 4; ++mi) {
            const int R = wr * 128 + mih * 64 + mi * 16 + cl;
            fa[mi] = *(const s16x8*)(base + R * 64 + ((rg ^ gc) << 4));
        }
    };
    auto ldB = [&](int pb, int kk, s16x8* fb) {
        const char* base = (const char*)&LS[pb][1][kk][0];
        #pragma unroll
        for (int ni = 0; ni < 4; ++ni) {
            const int R = wc * 64 + ni * 16 + cl;
            fb[ni] = *(const s16x8*)(base + R * 64 + ((rg ^ gc) << 4));
        }
    };

    const int nt = KD / 64;
    // prologue: tile 0 complete + tile 1 kk0 (12 loads/thread); need tile 0.
    stageU(0, 0, 0); stageU(1, 0, 0); stageU(0, 1, 0); stageU(1, 1, 0);
    stageU(0, 0, 1); stageU(1, 0, 1);
    asm volatile("s_waitcnt vmcnt(4)" ::: "memory");
    __builtin_amdgcn_s_barrier();

    s16x8 fa[4], fb[4];
    for (int t = 0; t < nt; ++t) {
        const int pb = t & 1;
        // ---- phase 0: kk0, M-half 0 ----
        if (t + 1 < nt) stageU(0, 1, t + 1);
        ldA(pb, 0, 0, fa); ldB(pb, 0, fb);
        __builtin_amdgcn_s_barrier();
        asm volatile("s_waitcnt lgkmcnt(0)" ::: "memory");
        __builtin_amdgcn_sched_barrier(0);
        __builtin_amdgcn_s_setprio(1);
        #pragma unroll
        for (int ni = 0; ni < 4; ++ni)
            #pragma unroll
            for (int mi = 0; mi < 4; ++mi)
                acc[mi][ni] = MFMA16(fa[mi], fb[ni], acc[mi][ni]);
        __builtin_amdgcn_s_setprio(0);
        __builtin_amdgcn_s_barrier();
        // ---- phase 1: kk0, M-half 1 ----
        if (t + 1 < nt) stageU(1, 1, t + 1);
        ldA(pb, 0, 1, fa);
        __builtin_amdgcn_s_barrier();
        asm volatile("s_waitcnt lgkmcnt(0)" ::: "memory");
        __builtin_amdgcn_sched_barrier(0);
        __builtin_amdgcn_s_setprio(1);
        #pragma unroll
        for (int ni = 0; ni < 4; ++ni)
            #pragma unroll
            for (int mi = 0; mi < 4; ++mi)
                acc[4 + mi][ni] = MFMA16(fa[mi], fb[ni], acc[4 + mi][ni]);
        __builtin_amdgcn_s_setprio(0);
        __builtin_amdgcn_s_barrier();
        // ---- phase 2: kk1, M-half 0 ----
        if (t + 2 < nt) stageU(0, 0, t + 2);
        ldA(pb, 1, 0, fa); ldB(pb, 1, fb);
        __builtin_amdgcn_s_barrier();
        asm volatile("s_waitcnt lgkmcnt(0)" ::: "memory");
        __builtin_amdgcn_sched_barrier(0);
        __builtin_amdgcn_s_setprio(1);
        #pragma unroll
        for (int ni = 0; ni < 4; ++ni)
            #pragma unroll
            for (int mi = 0; mi < 4; ++mi)
                acc[mi][ni] = MFMA16(fa[mi], fb[ni], acc[mi][ni]);
        __builtin_amdgcn_s_setprio(0);
        __builtin_amdgcn_s_barrier();
        // ---- phase 3: kk1, M-half 1 ----
        if (t + 2 < nt) stageU(1, 0, t + 2);
        ldA(pb, 1, 1, fa);
        __builtin_amdgcn_s_barrier();
        asm volatile("s_waitcnt lgkmcnt(0)" ::: "memory");
        __builtin_amdgcn_sched_barrier(0);
        __builtin_amdgcn_s_setprio(1);
        #pragma unroll
        for (int ni = 0; ni < 4; ++ni)
            #pragma unroll
            for (int mi = 0; mi < 4; ++mi)
                acc[4 + mi][ni] = MFMA16(fa[mi], fb[ni], acc[4 + mi][ni]);
        __builtin_amdgcn_s_setprio(0);
        // tile boundary: counted wait covering all of tile t+1's loads.
        if (t <= nt - 3) asm volatile("s_waitcnt vmcnt(4)" ::: "memory");
        else             asm volatile("s_waitcnt vmcnt(0)" ::: "memory");
        __builtin_amdgcn_s_barrier();
    }

    const int m0 = row0 + wr * 128, n0 = col0 + wc * 64;
    if (MODE == 0) {
        const int s = 1 + (col0 >> 10);       // 1:k 2:v, uniform per block
        #pragma unroll
        for (int ni = 0; ni < 4; ++ni) {
            const int col = n0 + ni * 16 + cl;
            const int h = (col & 1023) >> 6, dd = col & 63;
            #pragma unroll
            for (int mi = 0; mi < 8; ++mi)
                #pragma unroll
                for (int r = 0; r < 4; ++r) {
                    const int bt = m0 + mi * 16 + rg * 4 + r;
                    const int bb = bt >> 12, t = bt & (T_ - 1);
                    const size_t bh64 = (size_t)(bb * H_ + h);
                    const short sg = (acc[mi][ni][r] >= 0.f) ? (short)0x3F80
                                                             : (short)0xBF80;
                    const size_t otr = bh64 * ((size_t)T_ * 64)
                                     + (size_t)(t >> 6) * 4096 + dd * 64 + (t & 63);
                    if (s == 1) {
                        O1[(bh64 * T_ + t) * 64 + dd] = sg;   // Kb [c][d]
                        O2[otr] = sg;                         // KbT [d][c]
                    } else {
                        O3[otr] = sg;                         // VbT [d][c]
                    }
                }
        }
    } else if (MODE == 2) {
        #pragma unroll
        for (int ni = 0; ni < 4; ++ni) {
            const int col = n0 + ni * 16 + cl;
            const int h = col >> 6, dd = col & 63;
            #pragma unroll
            for (int mi = 0; mi < 8; ++mi)
                #pragma unroll
                for (int r = 0; r < 4; ++r) {
                    const int bt = m0 + mi * 16 + rg * 4 + r;
                    const int bb = bt >> 12, t = bt & (T_ - 1);
                    O1[((size_t)(bb * H_ + h) * T_ + t) * 64 + dd] =
                        (short)f2bf(acc[mi][ni][r] * 0.125f);
                }
        }
    } else {
        #pragma unroll
        for (int ni = 0; ni < 4; ++ni) {
            const int col = n0 + ni * 16 + cl;
            #pragma unroll
            for (int mi = 0; mi < 8; ++mi)
                #pragma unroll
                for (int r = 0; r < 4; ++r)
                    Yf[(size_t)(m0 + mi * 16 + rg * 4 + r) * D_ + col] =
                        acc[mi][ni][r];
        }
    }
}

// ---------------------------------------------------------------------------
// K2 (MFMA): per chunk: S = mask(Q K^T); intra = S V^T-op -> OMi bf16;
// ckvT[dd][kd] = sum_c v[c][dd] k[c][kd] -> CKV8 int8 (exact small ints).
// ---------------------------------------------------------------------------
__global__ __launch_bounds__(256)
void k_chunk2(const short* __restrict__ Qb, const short* __restrict__ Kb,
              const short* __restrict__ KbT, const short* __restrict__ VbT,
              short* __restrict__ OMi, signed char* __restrict__ CKV8)
{
    __shared__ __align__(16) short Qs[4096], Ks[4096], KTs[4096], VTs[4096], Ss[4096];
    const int tid = threadIdx.x;
    const int bh = blockIdx.x >> 6, n = blockIdx.x & 63;
    const size_t cbase = ((size_t)bh * T_ + n * 64) * 64;

    auto stage_tile = [&](const short* g, short* l) {
        #pragma unroll
        for (int p = 0; p < 2; ++p) {
            const int off = tid * 16 + p * 4096;
            const int r = off >> 7;
            s16x8 v = *(const s16x8*)(g + (off >> 1));
            *(s16x8*)((char*)l + (off ^ ((r & 7) << 4))) = v;
        }
    };
    stage_tile(Qb  + cbase, Qs);
    stage_tile(Kb  + cbase, Ks);
    stage_tile(KbT + cbase, KTs);
    stage_tile(VbT + cbase, VTs);
    __syncthreads();

    const int lane = tid & 63, w = tid >> 6;
    const int cl = lane & 15, rg = lane >> 4;

    auto frag = [&](const short* l, int rowbase, int kk) -> s16x8 {
        const int row = rowbase + cl;
        int off = row * 128 + kk * 64 + rg * 16;
        off ^= (row & 7) << 4;
        return *(const s16x8*)((const char*)l + off);
    };

    // phase 1: S = Q K^T (masked), bf16 -> Ss
    {
        f32x4 a1[4];
        #pragma unroll
        for (int ni = 0; ni < 4; ++ni) a1[ni] = (f32x4)0.f;
        const s16x8 qa0 = frag(Qs, w * 16, 0), qa1 = frag(Qs, w * 16, 1);
        #pragma unroll
        for (int ni = 0; ni < 4; ++ni) {
            a1[ni] = MFMA16(qa0, frag(Ks, ni * 16, 0), a1[ni]);
            a1[ni] = MFMA16(qa1, frag(Ks, ni * 16, 1), a1[ni]);
        }
        #pragma unroll
        for (int ni = 0; ni < 4; ++ni)
            #pragma unroll
            for (int r = 0; r < 4; ++r) {
                const int i = w * 16 + rg * 4 + r, j = ni * 16 + cl;
                const float v = (j <= i) ? a1[ni][r] : 0.f;
                const int off = (i * 128 + j * 2) ^ ((i & 7) << 4);
                *(short*)((char*)Ss + off) = (short)f2bf(v);
            }
    }
    __syncthreads();

    // phase 2: intra = S * V; phase 3: ckvT[dd][kd]
    f32x4 a2[4], a3[4];
    #pragma unroll
    for (int ni = 0; ni < 4; ++ni) { a2[ni] = (f32x4)0.f; a3[ni] = (f32x4)0.f; }
    {
        const s16x8 sa0 = frag(Ss, w * 16, 0),  sa1 = frag(Ss, w * 16, 1);
        const s16x8 va0 = frag(VTs, w * 16, 0), va1 = frag(VTs, w * 16, 1);
        #pragma unroll
        for (int ni = 0; ni < 4; ++ni) {
            a2[ni] = MFMA16(sa0, frag(VTs, ni * 16, 0), a2[ni]);
            a2[ni] = MFMA16(sa1, frag(VTs, ni * 16, 1), a2[ni]);
            a3[ni] = MFMA16(va0, frag(KTs, ni * 16, 0), a3[ni]);
            a3[ni] = MFMA16(va1, frag(KTs, ni * 16, 1), a3[ni]);
        }
    }
    #pragma unroll
    for (int ni = 0; ni < 4; ++ni)
        #pragma unroll
        for (int r = 0; r < 4; ++r) {
            const int m = w * 16 + rg * 4 + r;     // i for intra, dd for ckv
            const int c = ni * 16 + cl;            // dd for intra, kd for ckv
            const int off = (m * 128 + c * 2) ^ ((m & 7) << 4);
            *(short*)((char*)Qs + off) = (short)f2bf(a2[ni][r]);
            ((signed char*)Ks)[m * 64 + c] = (signed char)(int)a3[ni][r];
        }
    __syncthreads();

    const int bb = bh >> 4, h = bh & 15;
    #pragma unroll
    for (int p = 0; p < 2; ++p) {
        const int off = tid * 16 + p * 4096;
        const int r = off >> 7;
        const int lo = off ^ ((r & 7) << 4);
        s16x8 v = *(const s16x8*)((char*)Qs + lo);
        const size_t gi = ((size_t)bb * T_ + n * 64 + r) * D_
                        + h * 64 + ((off & 127) >> 1);
        *(s16x8*)(OMi + gi) = v;
    }
    {
        const size_t c8 = ((size_t)bh * 64 + n) * 4096;
        *(int4*)(CKV8 + c8 + tid * 16) = *(const int4*)((const char*)Ks + tid * 16);
    }
}

// ---------------------------------------------------------------------------
// K3: integer exclusive scan of CKV8 over chunks -> PB bf16; FM fp32 exact.
// ---------------------------------------------------------------------------
__global__ __launch_bounds__(256)
void k_scan2(const signed char* __restrict__ CKV8, short* __restrict__ PB,
             float* __restrict__ FM, float* __restrict__ FC)
{
    const int bh = blockIdx.x >> 4;
    const int e  = (blockIdx.x & 15) * 256 + threadIdx.x;   // dd*64+kd
    const size_t b8 = (size_t)bh * N_ * 4096 + e;
    const size_t bp = (size_t)bh * N_ * 4096 + e;
    int run = 0;
    #pragma unroll
    for (int nn = 0; nn < 64; ++nn) {
        PB[bp + (size_t)nn * 4096] = (short)f2bf((float)run);
        run += (int)CKV8[b8 + (size_t)nn * 4096];
    }
    FM[(size_t)bh * 4096 + (e & 63) * 64 + (e >> 6)] = (float)run;
    if ((blockIdx.x & 15) == 0 && threadIdx.x == 0) FC[bh] = (float)T_;
}

// ---------------------------------------------------------------------------
// K4 (MFMA): cross = Q @ prefix; OMb = bf16((OMi + cross) / total).
// ---------------------------------------------------------------------------
__global__ __launch_bounds__(256)
void k_cross2(const short* __restrict__ Qb, const short* __restrict__ PB,
              const short* __restrict__ OMi, short* __restrict__ OMb)
{
    __shared__ __align__(16) short Qs[4096], Ps[4096], Cs[4096];
    const int tid = threadIdx.x;
    const int bh = blockIdx.x >> 6, n = blockIdx.x & 63;
    const size_t cbase = ((size_t)bh * T_ + n * 64) * 64;

    auto stage_tile = [&](const short* g, short* l) {
        #pragma unroll
        for (int p = 0; p < 2; ++p) {
            const int off = tid * 16 + p * 4096;
            const int r = off >> 7;
            s16x8 v = *(const s16x8*)(g + (off >> 1));
            *(s16x8*)((char*)l + (off ^ ((r & 7) << 4))) = v;
        }
    };
    stage_tile(Qb + cbase, Qs);
    stage_tile(PB + ((size_t)bh * 64 + n) * 4096, Ps);
    __syncthreads();

    const int lane = tid & 63, w = tid >> 6;
    const int cl = lane & 15, rg = lane >> 4;

    auto frag = [&](const short* l, int rowbase, int kk) -> s16x8 {
        const int row = rowbase + cl;
        int off = row * 128 + kk * 64 + rg * 16;
        off ^= (row & 7) << 4;
        return *(const s16x8*)((const char*)l + off);
    };

    f32x4 a1[4];
    #pragma unroll
    for (int ni = 0; ni < 4; ++ni) a1[ni] = (f32x4)0.f;
    const s16x8 qa0 = frag(Qs, w * 16, 0), qa1 = frag(Qs, w * 16, 1);
    #pragma unroll
    for (int ni = 0; ni < 4; ++ni) {
        a1[ni] = MFMA16(qa0, frag(Ps, ni * 16, 0), a1[ni]);
        a1[ni] = MFMA16(qa1, frag(Ps, ni * 16, 1), a1[ni]);
    }
    #pragma unroll
    for (int ni = 0; ni < 4; ++ni)
        #pragma unroll
        for (int r = 0; r < 4; ++r) {
            const int i = w * 16 + rg * 4 + r, j = ni * 16 + cl;
            const int off = (i * 128 + j * 2) ^ ((i & 7) << 4);
            *(short*)((char*)Cs + off) = (short)f2bf(a1[ni][r]);
        }
    __syncthreads();

    const int bb = bh >> 4, h = bh & 15;
    #pragma unroll
    for (int p = 0; p < 2; ++p) {
        const int off = tid * 16 + p * 4096;
        const int r = off >> 7;
        const int lo = off ^ ((r & 7) << 4);
        s16x8 cv = *(const s16x8*)((char*)Cs + lo);
        const size_t gi = ((size_t)bb * T_ + n * 64 + r) * D_
                        + h * 64 + ((off & 127) >> 1);
        s16x8 iv = *(const s16x8*)(OMi + gi);
        const float invt = 1.0f / (float)(n * 64 + r + 1);
        s16x8 ov;
        #pragma unroll
        for (int j = 0; j < 8; ++j) {
            const float f = (bf2f((unsigned short)iv[j])
                           + bf2f((unsigned short)cv[j])) * invt;
            ov[j] = (short)f2bf(f);
        }
        *(s16x8*)(OMb + gi) = ov;
    }
}

extern "C" void kernel_launch(void* const* d_in, const int* in_sizes, int n_in,
                              void* d_out, int out_size, void* d_ws, size_t ws_size,
                              hipStream_t stream)
{
    const float* X    = (const float*)d_in[0];
    const float* Wqkv = (const float*)d_in[1];
    const float* Wo   = (const float*)d_in[2];

    float* Y  = (float*)d_out;                       // [B,T,D]
    float* FM = Y + (size_t)B_ * T_ * D_;            // [B,H,64,64]
    float* FC = FM + (size_t)B_ * H_ * HD_ * HD_;    // [B,H,1,1]

    char* ws = (char*)d_ws;
    const size_t Mi = 1048576;
    short*       Qb   = (short*)(ws + 0 * Mi);     // 32 MiB
    short*       Kb   = (short*)(ws + 32 * Mi);    // 32 MiB
    short*       KbT  = (short*)(ws + 64 * Mi);    // 32 MiB (early)
    short*       PB   = (short*)(ws + 64 * Mi);    // 32 MiB (late, over KbT)
    short*       VbT  = (short*)(ws + 96 * Mi);    // 32 MiB
    short*       XS   = (short*)(ws + 128 * Mi);   // 64 MiB (early)
    short*       Xb   = (short*)(ws + 128 * Mi);   // 32 MiB (mid, over XS)
    short*       OMi  = (short*)(ws + 128 * Mi);   // 32 MiB (late, over Xb)
    short*       OMb  = (short*)(ws + 160 * Mi);   // 32 MiB
    short*       WSq  = (short*)(ws + 192 * Mi);   //  8 MiB (early)
    signed char* CKV8 = (signed char*)(ws + 192 * Mi); // 16 MiB (late)
    short*       Wqb  = (short*)(ws + 208 * Mi);   //  2 MiB
    short*       WoS  = (short*)(ws + 210 * Mi);   //  2 MiB
    if (ws_size < (size_t)222 * Mi) return;

    dim3 blk(256), blkg(512);
    // X (split) and W_kv (split, rows 1024..3071 of Wqkv)
    k_cvt_split<<<dim3(2048), blk, 0, stream>>>(X, XS, 4194304);
    k_cvt_split<<<dim3(1024), blk, 0, stream>>>(Wqkv + (size_t)1024 * 1024, WSq, 524288);
    // K/V GEMM: split K=2048, N=2048 (256^2 tiles, 8-phase)
    k_gemm<0, 2048, 8><<<dim3(512), blkg, 0, stream>>>(XS, WSq, Kb, KbT, VbT, nullptr);
    // Q GEMM: plain bf16 K=1024 (Xb overwrites XS after kv-GEMM done)
    k_cvt<<<dim3(2048), blk, 0, stream>>>(X, Xb, 4194304);
    k_cvt<<<dim3(512),  blk, 0, stream>>>(Wqkv, Wqb, 262144);
    k_gemm<2, 1024, 4><<<dim3(256), blkg, 0, stream>>>(Xb, Wqb, Qb, nullptr, nullptr, nullptr);
    // chunk-local MFMA work
    k_chunk2<<<dim3(4096), blk, 0, stream>>>(Qb, Kb, KbT, VbT, OMi, CKV8);
    k_scan2 <<<dim3(1024), blk, 0, stream>>>(CKV8, PB, FM, FC);
    k_cross2<<<dim3(4096), blk, 0, stream>>>(Qb, PB, OMi, OMb);
    // output GEMM
    k_cvt<<<dim3(512), blk, 0, stream>>>(Wo, WoS, 262144);
    k_gemm<1, 1024, 4><<<dim3(256), blkg, 0, stream>>>(OMb, WoS, nullptr, nullptr, nullptr, Y);
}

// Round 7
// 372.726 us; speedup vs baseline: 1.0290x; 1.0290x over previous
//
#include <hip/hip_runtime.h>
#include <cstdint>

// B=4, T=4096, D=1024, H=16, d=64, C=64, N=T/C=64
#define B_ 4
#define T_ 4096
#define D_ 1024
#define H_ 16
#define HD_ 64
#define N_ 64

typedef __attribute__((ext_vector_type(8))) short s16x8;
typedef __attribute__((ext_vector_type(4))) float f32x4;

__device__ __forceinline__ unsigned short f2bf(float f) {
    unsigned int u = __builtin_bit_cast(unsigned int, f);
    u += 0x7fffu + ((u >> 16) & 1u);          // RNE
    return (unsigned short)(u >> 16);
}
__device__ __forceinline__ float bf2f(unsigned short h) {
    unsigned int u = ((unsigned int)h) << 16;
    return __builtin_bit_cast(float, u);
}
__device__ __forceinline__ void gl2lds(const short* g, short* l) {
    __builtin_amdgcn_global_load_lds(
        (const __attribute__((address_space(1))) void*)g,
        (__attribute__((address_space(3))) void*)l, 16, 0, 0);
}
#define MFMA16(a, b, c) __builtin_amdgcn_mfma_f32_16x16x32_bf16(a, b, c, 0, 0, 0)

// ---------------------------------------------------------------------------
// Converters.
// ---------------------------------------------------------------------------
__global__ __launch_bounds__(256)
void k_cvt_split(const float* __restrict__ in, short* __restrict__ out, int n4)
{
    int i = blockIdx.x * blockDim.x + threadIdx.x;
    const int stride = gridDim.x * blockDim.x;
    for (; i < n4; i += stride) {
        float4 f = ((const float4*)in)[i];
        const float v[4] = {f.x, f.y, f.z, f.w};
        s16x8 o;
        #pragma unroll
        for (int j = 0; j < 4; ++j) {
            unsigned short h = f2bf(v[j]);
            o[j*2]   = (short)h;
            o[j*2+1] = (short)f2bf(v[j] - bf2f(h));
        }
        ((s16x8*)out)[i] = o;
    }
}
__global__ __launch_bounds__(256)
void k_cvt(const float* __restrict__ in, short* __restrict__ out, int n4)
{
    int i = blockIdx.x * blockDim.x + threadIdx.x;
    const int stride = gridDim.x * blockDim.x;
    for (; i < n4; i += stride) {
        float4 f = ((const float4*)in)[i];
        short4 o;
        o.x = (short)f2bf(f.x); o.y = (short)f2bf(f.y);
        o.z = (short)f2bf(f.z); o.w = (short)f2bf(f.w);
        *(short4*)(out + i * 4) = o;
    }
}

// ---------------------------------------------------------------------------
// bf16 MFMA GEMM: O = A @ B^T. A [16384][KD], B [256*NCB][KD] bf16.
// 256x256 tile, BK=64, 512 thr (8 waves, 2x4), 16x16x32 MFMA.
// gl2lds staging (pre-swizzled global src, linear LDS dest), double-buffered
// 128 KiB LDS, counted vmcnt(8). The barrier region contains BOTH the
// ds_reads and the 64 MFMAs with NO manual lgkmcnt drain / setprio fences:
// the compiler emits fine-grained counted lgkmcnt and interleaves reads
// under MFMAs (m97 behavior). sched_barrier(0) pins only the region edges
// (reads must not hoist above the opening barrier nor sink past the closing
// one, where the buffer gets re-staged). Swizzle: 128B rows, phys 16B slot
// = logical ^ (row&7) (round-5 layout, measured 0 conflicts).
// MODE 0: k/v epilogue (sign bf16 -> Kb+KbT or VbT). MODE 1: fp32 Y.
// MODE 2: Q epilogue (bf16, *0.125).
// ---------------------------------------------------------------------------
template<int MODE, int KD, int NCB>
__global__ __launch_bounds__(512, 2)
void k_gemm(const short* __restrict__ A, const short* __restrict__ Bm,
            short* __restrict__ O1, short* __restrict__ O2,
            short* __restrict__ O3, float* __restrict__ Yf)
{
    __shared__ __align__(16) short LS[2][2][16384];   // [dbuf][A/B][256*64]

    const int tid = threadIdx.x;
    const int nwg = 64 * NCB;
    const int bid = blockIdx.x;
    const int sz  = (bid & 7) * (nwg >> 3) + (bid >> 3);   // XCD-contiguous
    const int cb  = sz % NCB, rb = sz / NCB;
    const int row0 = rb * 256, col0 = cb * 256;

    const int lane = tid & 63, w = tid >> 6;
    const int wr = w >> 2, wc = w & 3;
    const int cl = lane & 15, rg = lane >> 4;

    // staging: wave w owns 32 rows of each tile; 4 calls x 8 rows, lane
    // l -> row (l>>3), phys slot (l&7); global src slot = (l&7)^(l>>3).
    const int sr8 = lane >> 3;
    const int slg = ((lane & 7) ^ sr8) * 8;
    const short* gA = A  + (size_t)(row0 + w * 32 + sr8) * KD + slg;
    const short* gB = Bm + (size_t)(col0 + w * 32 + sr8) * KD + slg;

    f32x4 acc[8][4];
    #pragma unroll
    for (int i = 0; i < 8; ++i)
        #pragma unroll
        for (int j = 0; j < 4; ++j) acc[i][j] = (f32x4)0.f;

    auto stage = [&](int pb2, int t2) {
        const int ko = t2 * 64;
        #pragma unroll
        for (int c = 0; c < 4; ++c) {
            gl2lds(gA + ko + c * 8 * KD, &LS[pb2][0][(w * 32 + c * 8) * 64]);
            gl2lds(gB + ko + c * 8 * KD, &LS[pb2][1][(w * 32 + c * 8) * 64]);
        }
    };
    // swizzled fragment read: logical slot q (0..7) of row R
    auto ldrd = [&](const short* base, int R, int q) -> s16x8 {
        const int off = R * 128 + (((q) ^ (R & 7)) << 4);
        return *(const s16x8*)((const char*)base + off);
    };

    const int nt = KD / 64;
    stage(0, 0);
    for (int t = 0; t < nt; ++t) {
        const int pb = t & 1;
        if (t + 1 < nt) {
            stage(pb ^ 1, t + 1);
            asm volatile("s_waitcnt vmcnt(8)" ::: "memory");
        } else {
            asm volatile("s_waitcnt vmcnt(0)" ::: "memory");
        }
        __builtin_amdgcn_s_barrier();
        __builtin_amdgcn_sched_barrier(0);

        const short* bA = &LS[pb][0][0];
        const short* bB = &LS[pb][1][0];
        s16x8 fb[2][4];
        #pragma unroll
        for (int kk = 0; kk < 2; ++kk)
            #pragma unroll
            for (int ni = 0; ni < 4; ++ni)
                fb[kk][ni] = ldrd(bB, wc * 64 + ni * 16 + cl, kk * 4 + rg);

        // 4 groups of {4 fa reads -> 16 MFMA}; compiler interleaves freely.
        #pragma unroll
        for (int g = 0; g < 4; ++g) {
            const int kk = g >> 1, mih = g & 1;
            s16x8 fa[4];
            #pragma unroll
            for (int mi = 0; mi < 4; ++mi)
                fa[mi] = ldrd(bA, wr * 128 + mih * 64 + mi * 16 + cl,
                              kk * 4 + rg);
            #pragma unroll
            for (int ni = 0; ni < 4; ++ni)
                #pragma unroll
                for (int mi = 0; mi < 4; ++mi)
                    acc[mih * 4 + mi][ni] =
                        MFMA16(fa[mi], fb[kk][ni], acc[mih * 4 + mi][ni]);
        }

        __builtin_amdgcn_sched_barrier(0);
        __builtin_amdgcn_s_barrier();
    }

    const int m0 = row0 + wr * 128, n0 = col0 + wc * 64;
    if (MODE == 0) {
        const int s = 1 + (col0 >> 10);       // 1:k 2:v, uniform per block
        #pragma unroll
        for (int ni = 0; ni < 4; ++ni) {
            const int col = n0 + ni * 16 + cl;
            const int h = (col & 1023) >> 6, dd = col & 63;
            #pragma unroll
            for (int mi = 0; mi < 8; ++mi)
                #pragma unroll
                for (int r = 0; r < 4; ++r) {
                    const int bt = m0 + mi * 16 + rg * 4 + r;
                    const int bb = bt >> 12, t = bt & (T_ - 1);
                    const size_t bh64 = (size_t)(bb * H_ + h);
                    const short sg = (acc[mi][ni][r] >= 0.f) ? (short)0x3F80
                                                             : (short)0xBF80;
                    const size_t otr = bh64 * ((size_t)T_ * 64)
                                     + (size_t)(t >> 6) * 4096 + dd * 64 + (t & 63);
                    if (s == 1) {
                        O1[(bh64 * T_ + t) * 64 + dd] = sg;   // Kb [c][d]
                        O2[otr] = sg;                         // KbT [d][c]
                    } else {
                        O3[otr] = sg;                         // VbT [d][c]
                    }
                }
        }
    } else if (MODE == 2) {
        #pragma unroll
        for (int ni = 0; ni < 4; ++ni) {
            const int col = n0 + ni * 16 + cl;
            const int h = col >> 6, dd = col & 63;
            #pragma unroll
            for (int mi = 0; mi < 8; ++mi)
                #pragma unroll
                for (int r = 0; r < 4; ++r) {
                    const int bt = m0 + mi * 16 + rg * 4 + r;
                    const int bb = bt >> 12, t = bt & (T_ - 1);
                    O1[((size_t)(bb * H_ + h) * T_ + t) * 64 + dd] =
                        (short)f2bf(acc[mi][ni][r] * 0.125f);
                }
        }
    } else {
        #pragma unroll
        for (int ni = 0; ni < 4; ++ni) {
            const int col = n0 + ni * 16 + cl;
            #pragma unroll
            for (int mi = 0; mi < 8; ++mi)
                #pragma unroll
                for (int r = 0; r < 4; ++r)
                    Yf[(size_t)(m0 + mi * 16 + rg * 4 + r) * D_ + col] =
                        acc[mi][ni][r];
        }
    }
}

// ---------------------------------------------------------------------------
// K2 (MFMA): per chunk: S = mask(Q K^T); intra = S V^T-op -> OMi bf16;
// ckvT[dd][kd] = sum_c v[c][dd] k[c][kd] -> CKV8 int8 (exact small ints).
// ---------------------------------------------------------------------------
__global__ __launch_bounds__(256)
void k_chunk2(const short* __restrict__ Qb, const short* __restrict__ Kb,
              const short* __restrict__ KbT, const short* __restrict__ VbT,
              short* __restrict__ OMi, signed char* __restrict__ CKV8)
{
    __shared__ __align__(16) short Qs[4096], Ks[4096], KTs[4096], VTs[4096], Ss[4096];
    const int tid = threadIdx.x;
    const int bh = blockIdx.x >> 6, n = blockIdx.x & 63;
    const size_t cbase = ((size_t)bh * T_ + n * 64) * 64;

    auto stage_tile = [&](const short* g, short* l) {
        #pragma unroll
        for (int p = 0; p < 2; ++p) {
            const int off = tid * 16 + p * 4096;
            const int r = off >> 7;
            s16x8 v = *(const s16x8*)(g + (off >> 1));
            *(s16x8*)((char*)l + (off ^ ((r & 7) << 4))) = v;
        }
    };
    stage_tile(Qb  + cbase, Qs);
    stage_tile(Kb  + cbase, Ks);
    stage_tile(KbT + cbase, KTs);
    stage_tile(VbT + cbase, VTs);
    __syncthreads();

    const int lane = tid & 63, w = tid >> 6;
    const int cl = lane & 15, rg = lane >> 4;

    auto frag = [&](const short* l, int rowbase, int kk) -> s16x8 {
        const int row = rowbase + cl;
        int off = row * 128 + kk * 64 + rg * 16;
        off ^= (row & 7) << 4;
        return *(const s16x8*)((const char*)l + off);
    };

    // phase 1: S = Q K^T (masked), bf16 -> Ss
    {
        f32x4 a1[4];
        #pragma unroll
        for (int ni = 0; ni < 4; ++ni) a1[ni] = (f32x4)0.f;
        const s16x8 qa0 = frag(Qs, w * 16, 0), qa1 = frag(Qs, w * 16, 1);
        #pragma unroll
        for (int ni = 0; ni < 4; ++ni) {
            a1[ni] = MFMA16(qa0, frag(Ks, ni * 16, 0), a1[ni]);
            a1[ni] = MFMA16(qa1, frag(Ks, ni * 16, 1), a1[ni]);
        }
        #pragma unroll
        for (int ni = 0; ni < 4; ++ni)
            #pragma unroll
            for (int r = 0; r < 4; ++r) {
                const int i = w * 16 + rg * 4 + r, j = ni * 16 + cl;
                const float v = (j <= i) ? a1[ni][r] : 0.f;
                const int off = (i * 128 + j * 2) ^ ((i & 7) << 4);
                *(short*)((char*)Ss + off) = (short)f2bf(v);
            }
    }
    __syncthreads();

    // phase 2: intra = S * V; phase 3: ckvT[dd][kd]
    f32x4 a2[4], a3[4];
    #pragma unroll
    for (int ni = 0; ni < 4; ++ni) { a2[ni] = (f32x4)0.f; a3[ni] = (f32x4)0.f; }
    {
        const s16x8 sa0 = frag(Ss, w * 16, 0),  sa1 = frag(Ss, w * 16, 1);
        const s16x8 va0 = frag(VTs, w * 16, 0), va1 = frag(VTs, w * 16, 1);
        #pragma unroll
        for (int ni = 0; ni < 4; ++ni) {
            a2[ni] = MFMA16(sa0, frag(VTs, ni * 16, 0), a2[ni]);
            a2[ni] = MFMA16(sa1, frag(VTs, ni * 16, 1), a2[ni]);
            a3[ni] = MFMA16(va0, frag(KTs, ni * 16, 0), a3[ni]);
            a3[ni] = MFMA16(va1, frag(KTs, ni * 16, 1), a3[ni]);
        }
    }
    #pragma unroll
    for (int ni = 0; ni < 4; ++ni)
        #pragma unroll
        for (int r = 0; r < 4; ++r) {
            const int m = w * 16 + rg * 4 + r;     // i for intra, dd for ckv
            const int c = ni * 16 + cl;            // dd for intra, kd for ckv
            const int off = (m * 128 + c * 2) ^ ((m & 7) << 4);
            *(short*)((char*)Qs + off) = (short)f2bf(a2[ni][r]);
            ((signed char*)Ks)[m * 64 + c] = (signed char)(int)a3[ni][r];
        }
    __syncthreads();

    const int bb = bh >> 4, h = bh & 15;
    #pragma unroll
    for (int p = 0; p < 2; ++p) {
        const int off = tid * 16 + p * 4096;
        const int r = off >> 7;
        const int lo = off ^ ((r & 7) << 4);
        s16x8 v = *(const s16x8*)((char*)Qs + lo);
        const size_t gi = ((size_t)bb * T_ + n * 64 + r) * D_
                        + h * 64 + ((off & 127) >> 1);
        *(s16x8*)(OMi + gi) = v;
    }
    {
        const size_t c8 = ((size_t)bh * 64 + n) * 4096;
        *(int4*)(CKV8 + c8 + tid * 16) = *(const int4*)((const char*)Ks + tid * 16);
    }
}

// ---------------------------------------------------------------------------
// K3: integer exclusive scan of CKV8 over chunks -> PB bf16; FM fp32 exact.
// ---------------------------------------------------------------------------
__global__ __launch_bounds__(256)
void k_scan2(const signed char* __restrict__ CKV8, short* __restrict__ PB,
             float* __restrict__ FM, float* __restrict__ FC)
{
    const int bh = blockIdx.x >> 4;
    const int e  = (blockIdx.x & 15) * 256 + threadIdx.x;   // dd*64+kd
    const size_t b8 = (size_t)bh * N_ * 4096 + e;
    const size_t bp = (size_t)bh * N_ * 4096 + e;
    int run = 0;
    #pragma unroll
    for (int nn = 0; nn < 64; ++nn) {
        PB[bp + (size_t)nn * 4096] = (short)f2bf((float)run);
        run += (int)CKV8[b8 + (size_t)nn * 4096];
    }
    FM[(size_t)bh * 4096 + (e & 63) * 64 + (e >> 6)] = (float)run;
    if ((blockIdx.x & 15) == 0 && threadIdx.x == 0) FC[bh] = (float)T_;
}

// ---------------------------------------------------------------------------
// K4 (MFMA): cross = Q @ prefix; OMb = bf16((OMi + cross) / total).
// ---------------------------------------------------------------------------
__global__ __launch_bounds__(256)
void k_cross2(const short* __restrict__ Qb, const short* __restrict__ PB,
              const short* __restrict__ OMi, short* __restrict__ OMb)
{
    __shared__ __align__(16) short Qs[4096], Ps[4096], Cs[4096];
    const int tid = threadIdx.x;
    const int bh = blockIdx.x >> 6, n = blockIdx.x & 63;
    const size_t cbase = ((size_t)bh * T_ + n * 64) * 64;

    auto stage_tile = [&](const short* g, short* l) {
        #pragma unroll
        for (int p = 0; p < 2; ++p) {
            const int off = tid * 16 + p * 4096;
            const int r = off >> 7;
            s16x8 v = *(const s16x8*)(g + (off >> 1));
            *(s16x8*)((char*)l + (off ^ ((r & 7) << 4))) = v;
        }
    };
    stage_tile(Qb + cbase, Qs);
    stage_tile(PB + ((size_t)bh * 64 + n) * 4096, Ps);
    __syncthreads();

    const int lane = tid & 63, w = tid >> 6;
    const int cl = lane & 15, rg = lane >> 4;

    auto frag = [&](const short* l, int rowbase, int kk) -> s16x8 {
        const int row = rowbase + cl;
        int off = row * 128 + kk * 64 + rg * 16;
        off ^= (row & 7) << 4;
        return *(const s16x8*)((const char*)l + off);
    };

    f32x4 a1[4];
    #pragma unroll
    for (int ni = 0; ni < 4; ++ni) a1[ni] = (f32x4)0.f;
    const s16x8 qa0 = frag(Qs, w * 16, 0), qa1 = frag(Qs, w * 16, 1);
    #pragma unroll
    for (int ni = 0; ni < 4; ++ni) {
        a1[ni] = MFMA16(qa0, frag(Ps, ni * 16, 0), a1[ni]);
        a1[ni] = MFMA16(qa1, frag(Ps, ni * 16, 1), a1[ni]);
    }
    #pragma unroll
    for (int ni = 0; ni < 4; ++ni)
        #pragma unroll
        for (int r = 0; r < 4; ++r) {
            const int i = w * 16 + rg * 4 + r, j = ni * 16 + cl;
            const int off = (i * 128 + j * 2) ^ ((i & 7) << 4);
            *(short*)((char*)Cs + off) = (short)f2bf(a1[ni][r]);
        }
    __syncthreads();

    const int bb = bh >> 4, h = bh & 15;
    #pragma unroll
    for (int p = 0; p < 2; ++p) {
        const int off = tid * 16 + p * 4096;
        const int r = off >> 7;
        const int lo = off ^ ((r & 7) << 4);
        s16x8 cv = *(const s16x8*)((char*)Cs + lo);
        const size_t gi = ((size_t)bb * T_ + n * 64 + r) * D_
                        + h * 64 + ((off & 127) >> 1);
        s16x8 iv = *(const s16x8*)(OMi + gi);
        const float invt = 1.0f / (float)(n * 64 + r + 1);
        s16x8 ov;
        #pragma unroll
        for (int j = 0; j < 8; ++j) {
            const float f = (bf2f((unsigned short)iv[j])
                           + bf2f((unsigned short)cv[j])) * invt;
            ov[j] = (short)f2bf(f);
        }
        *(s16x8*)(OMb + gi) = ov;
    }
}

extern "C" void kernel_launch(void* const* d_in, const int* in_sizes, int n_in,
                              void* d_out, int out_size, void* d_ws, size_t ws_size,
                              hipStream_t stream)
{
    const float* X    = (const float*)d_in[0];
    const float* Wqkv = (const float*)d_in[1];
    const float* Wo   = (const float*)d_in[2];

    float* Y  = (float*)d_out;                       // [B,T,D]
    float* FM = Y + (size_t)B_ * T_ * D_;            // [B,H,64,64]
    float* FC = FM + (size_t)B_ * H_ * HD_ * HD_;    // [B,H,1,1]

    char* ws = (char*)d_ws;
    const size_t Mi = 1048576;
    short*       Qb   = (short*)(ws + 0 * Mi);     // 32 MiB
    short*       Kb   = (short*)(ws + 32 * Mi);    // 32 MiB
    short*       KbT  = (short*)(ws + 64 * Mi);    // 32 MiB (early)
    short*       PB   = (short*)(ws + 64 * Mi);    // 32 MiB (late, over KbT)
    short*       VbT  = (short*)(ws + 96 * Mi);    // 32 MiB
    short*       XS   = (short*)(ws + 128 * Mi);   // 64 MiB (early)
    short*       Xb   = (short*)(ws + 128 * Mi);   // 32 MiB (mid, over XS)
    short*       OMi  = (short*)(ws + 128 * Mi);   // 32 MiB (late, over Xb)
    short*       OMb  = (short*)(ws + 160 * Mi);   // 32 MiB
    short*       WSq  = (short*)(ws + 192 * Mi);   //  8 MiB (early)
    signed char* CKV8 = (signed char*)(ws + 192 * Mi); // 16 MiB (late)
    short*       Wqb  = (short*)(ws + 208 * Mi);   //  2 MiB
    short*       WoS  = (short*)(ws + 210 * Mi);   //  2 MiB
    if (ws_size < (size_t)222 * Mi) return;

    dim3 blk(256), blkg(512);
    // X (split) and W_kv (split, rows 1024..3071 of Wqkv)
    k_cvt_split<<<dim3(2048), blk, 0, stream>>>(X, XS, 4194304);
    k_cvt_split<<<dim3(1024), blk, 0, stream>>>(Wqkv + (size_t)1024 * 1024, WSq, 524288);
    // K/V GEMM: split K=2048, N=2048 (256^2 tiles, de-drained region)
    k_gemm<0, 2048, 8><<<dim3(512), blkg, 0, stream>>>(XS, WSq, Kb, KbT, VbT, nullptr);
    // Q GEMM: plain bf16 K=1024 (Xb overwrites XS after kv-GEMM done)
    k_cvt<<<dim3(2048), blk, 0, stream>>>(X, Xb, 4194304);
    k_cvt<<<dim3(512),  blk, 0, stream>>>(Wqkv, Wqb, 262144);
    k_gemm<2, 1024, 4><<<dim3(256), blkg, 0, stream>>>(Xb, Wqb, Qb, nullptr, nullptr, nullptr);
    // chunk-local MFMA work
    k_chunk2<<<dim3(4096), blk, 0, stream>>>(Qb, Kb, KbT, VbT, OMi, CKV8);
    k_scan2 <<<dim3(1024), blk, 0, stream>>>(CKV8, PB, FM, FC);
    k_cross2<<<dim3(4096), blk, 0, stream>>>(Qb, PB, OMi, OMb);
    // output GEMM
    k_cvt<<<dim3(512), blk, 0, stream>>>(Wo, WoS, 262144);
    k_gemm<1, 1024, 4><<<dim3(256), blkg, 0, stream>>>(OMb, WoS, nullptr, nullptr, nullptr, Y);
}